// Round 9
// baseline (3200.026 us; speedup 1.0000x reference)
//
#include <hip/hip_runtime.h>
#include <hip/hip_bf16.h>

// GraphSAGE fused gather + weighted-mean + Linear(256->128) + ReLU
// N=100000, K=16, D=128, V=1e6 rows (f32 table).
//
// Round 9 = round 7 (straight-line range-phased gathers, named accumulators)
// + two spill fixes:
//  (a) amdgpu_waves_per_eu(4,4): pin 4 waves/EU -> 128-VGPR budget; the
//      compiler no longer spills accs chasing 8-wave occupancy (LDS caps us
//      at ~4 blocks/CU regardless).
//  (b) inner 16-item sweep split into 2x8 with sched_barrier(0) -> at most
//      8 float4 row loads in flight (32 VGPR) instead of 16 (64 VGPR).
// Out-of-phase items load row 0 (L1-hot) with weight 0 -> no divergence,
// loads stay batched; all duplicates of a row land in its single phase ->
// ~280 MB of L3 capacity re-fetch becomes L3 hits.
// Phase 2 (bf16 MFMA vs W1T) + full-row epilogue unchanged from round 5.

#define NN 100000
#define KK 16
#define DD 128
#define MM 16          // nodes per wave
#define WPB 4          // waves per block
#define NPHASE 4
#define PHSZ 250000u   // V / NPHASE

typedef __attribute__((ext_vector_type(8))) short short8;   // 8 x bf16
typedef __attribute__((ext_vector_type(4))) float f32x4;

// ---- prep: W1T[d][k] = bf16(W1[k][d]) ----
__global__ __launch_bounds__(256)
void prep_w1t_kernel(const float* __restrict__ W1, __hip_bfloat16* __restrict__ W1T)
{
    const int tid = blockIdx.x * blockDim.x + threadIdx.x;  // 32768 threads
    const int d = tid >> 8;      // 0..127
    const int k = tid & 255;     // 0..255
    W1T[d * 256 + k] = __float2bfloat16(W1[k * DD + d]);
}

static __device__ __forceinline__ unsigned pk_bf16(float a, float b) {
    __hip_bfloat162 t;
    t.x = __float2bfloat16(a);
    t.y = __float2bfloat16(b);
    return *reinterpret_cast<unsigned*>(&t);
}

__global__ __launch_bounds__(256)
__attribute__((amdgpu_waves_per_eu(4, 4)))
void graphsage_kernel(const int* __restrict__ video_nodes,
                      const int* __restrict__ neighbors,
                      const float* __restrict__ neigh_weights,
                      const float* __restrict__ emb,
                      const __hip_bfloat16* __restrict__ W1T,
                      const float* __restrict__ b1,
                      float* __restrict__ out)
{
    __shared__ __hip_bfloat16 comb[WPB][MM][2 * DD];

    const int lane = threadIdx.x & 63;
    const int wib  = __builtin_amdgcn_readfirstlane(threadIdx.x >> 6);
    const int node0 = (blockIdx.x * WPB + wib) * MM;
    if (node0 >= NN) return;   // whole-wave exit; no barriers anywhere

    char* const slot = (char*)&comb[wib][0][0];
    const char* const embB = (const char*)emb;
    char* const outB = (char*)out;

    const int half = lane >> 5;               // which node of the pair
    const int c    = lane & 31;               // column group: floats 4c..4c+3
    const unsigned byte_c = 16u * (unsigned)c;

    // ---- self rows: unphased gather + pack (as round 5) ----
    #pragma unroll
    for (int mp = 0; mp < MM / 2; ++mp) {
        const int n0 = node0 + 2 * mp;
        const int s0i = video_nodes[n0];
        const int s1i = video_nodes[n0 + 1];
        const int sidx = half ? s1i : s0i;
        const float4 sv = *reinterpret_cast<const float4*>(
            embB + ((((unsigned)sidx) << 9) + byte_c));
        const int nodel = 2 * mp + half;
        const unsigned swz = (unsigned)((nodel & 7) << 4);
        const unsigned sb = ((unsigned)(nodel * 512) + 8u * c) ^ swz;
        uint2 sU;
        sU.x = pk_bf16(sv.x, sv.y);
        sU.y = pk_bf16(sv.z, sv.w);
        *reinterpret_cast<uint2*>(slot + sb) = sU;
    }

    // ---- neighbor accumulation: 4 index-range phases, named accumulators.
    // Out-of-phase items read row 0 (L1-hot) with weight 0: straight-line
    // code, loads stay batched; 2x8 split caps in-flight registers.
    f32x4 a0 = {0,0,0,0}, a1 = {0,0,0,0}, a2 = {0,0,0,0}, a3 = {0,0,0,0};
    f32x4 a4 = {0,0,0,0}, a5 = {0,0,0,0}, a6 = {0,0,0,0}, a7 = {0,0,0,0};

#define PAIR_HALF(M, AM, K0)                                                 \
    do {                                                                     \
        const int n0 = node0 + 2 * (M);                                      \
        _Pragma("unroll")                                                    \
        for (int k = (K0); k < (K0) + 8; ++k) {                              \
            const int   i0 = neighbors[n0 * KK + k];                         \
            const int   i1 = neighbors[(n0 + 1) * KK + k];                   \
            const float w0 = neigh_weights[n0 * KK + k];                     \
            const float w1 = neigh_weights[(n0 + 1) * KK + k];               \
            const int   rk = half ? i1 : i0;                                 \
            const float wk = half ? w1 : w0;                                 \
            const bool  inp = ((unsigned)rk - lo) < PHSZ;                    \
            const unsigned vo = inp ? ((((unsigned)rk) << 9) + byte_c)       \
                                    : byte_c;                                \
            const float wsel = inp ? wk : 0.0f;                              \
            const float4 e = *reinterpret_cast<const float4*>(embB + vo);    \
            AM[0] = fmaf(wsel, e.x, AM[0]);                                  \
            AM[1] = fmaf(wsel, e.y, AM[1]);                                  \
            AM[2] = fmaf(wsel, e.z, AM[2]);                                  \
            AM[3] = fmaf(wsel, e.w, AM[3]);                                  \
        }                                                                    \
        __builtin_amdgcn_sched_barrier(0);                                   \
    } while (0)

    #pragma unroll 1
    for (int p = 0; p < NPHASE; ++p) {
        const unsigned lo = (unsigned)p * PHSZ;
        PAIR_HALF(0, a0, 0); PAIR_HALF(0, a0, 8);
        PAIR_HALF(1, a1, 0); PAIR_HALF(1, a1, 8);
        PAIR_HALF(2, a2, 0); PAIR_HALF(2, a2, 8);
        PAIR_HALF(3, a3, 0); PAIR_HALF(3, a3, 8);
        PAIR_HALF(4, a4, 0); PAIR_HALF(4, a4, 8);
        PAIR_HALF(5, a5, 0); PAIR_HALF(5, a5, 8);
        PAIR_HALF(6, a6, 0); PAIR_HALF(6, a6, 8);
        PAIR_HALF(7, a7, 0); PAIR_HALF(7, a7, 8);
    }
#undef PAIR_HALF

    // ---- normalize + pack neighbor halves (wsum recomputed, L1-hot) ----
#define PACK_PAIR(M, AM)                                                     \
    do {                                                                     \
        const int n0 = node0 + 2 * (M);                                      \
        float s0 = 0.0f, s1 = 0.0f;                                          \
        _Pragma("unroll")                                                    \
        for (int k = 0; k < KK; ++k) {                                       \
            s0 += neigh_weights[n0 * KK + k];                                \
            s1 += neigh_weights[(n0 + 1) * KK + k];                          \
        }                                                                    \
        const float inv = 1.0f / (half ? s1 : s0);                           \
        const int nodel = 2 * (M) + half;                                    \
        const unsigned swz = (unsigned)((nodel & 7) << 4);                   \
        const unsigned nb = ((unsigned)(nodel * 512 + 256) + 8u * c) ^ swz;  \
        uint2 nU;                                                            \
        nU.x = pk_bf16(AM[0] * inv, AM[1] * inv);                            \
        nU.y = pk_bf16(AM[2] * inv, AM[3] * inv);                            \
        *reinterpret_cast<uint2*>(slot + nb) = nU;                           \
    } while (0)

    PACK_PAIR(0, a0);
    PACK_PAIR(1, a1);
    PACK_PAIR(2, a2);
    PACK_PAIR(3, a3);
    PACK_PAIR(4, a4);
    PACK_PAIR(5, a5);
    PACK_PAIR(6, a6);
    PACK_PAIR(7, a7);
#undef PACK_PAIR
    // wave-private slot: same-wave ds ordering via lgkmcnt + data deps.

    // ---- Phase 2: MFMA.  D[d][node] = sum_k W1T[d][k] * comb[node][k] ----
    const int nodeB  = lane & 15;    // B col / D col / output node
    const int kchunk = lane >> 4;    // 0..3
    const unsigned swzB = (unsigned)((nodeB & 7) << 4);

    short8 bfrag[8];
    #pragma unroll
    for (int kt = 0; kt < 8; ++kt) {
        const unsigned byte =
            ((unsigned)(nodeB * 512 + kt * 64 + kchunk * 16)) ^ swzB;
        bfrag[kt] = *reinterpret_cast<const short8*>(slot + byte);
    }

    const int drow = lane & 15;      // A row within d-tile
    #pragma unroll
    for (int dt = 0; dt < 8; ++dt) {
        const int d = dt * 16 + drow;
        f32x4 a = {0.0f, 0.0f, 0.0f, 0.0f};
        #pragma unroll
        for (int kt = 0; kt < 8; ++kt) {
            const short8 afrag = *reinterpret_cast<const short8*>(
                &W1T[d * 256 + kt * 32 + kchunk * 8]);
            a = __builtin_amdgcn_mfma_f32_16x16x32_bf16(afrag, bfrag[kt], a,
                                                        0, 0, 0);
        }
        const int d0 = dt * 16 + kchunk * 4;
        const float4 bias = *reinterpret_cast<const float4*>(&b1[d0]);
        f32x4 r;
        r[0] = fmaxf(a[0] + bias.x, 0.0f);
        r[1] = fmaxf(a[1] + bias.y, 0.0f);
        r[2] = fmaxf(a[2] + bias.z, 0.0f);
        r[3] = fmaxf(a[3] + bias.w, 0.0f);
        const unsigned tb = ((unsigned)(nodeB * 512 + d0 * 4)) ^ swzB;
        *reinterpret_cast<f32x4*>(slot + tb) = r;
    }

    // ---- Epilogue: linear LDS read -> full-row contiguous global stores ----
    #pragma unroll
    for (int i = 0; i < 8; ++i) {
        const unsigned o     = (unsigned)i * 1024u + (unsigned)lane * 16u;
        const unsigned nodel = o >> 9;
        const unsigned rb    = o & 511u;
        const unsigned lb    = nodel * 512u + (rb ^ ((nodel & 7u) << 4));
        const float4 v = *reinterpret_cast<const float4*>(slot + lb);
        *reinterpret_cast<float4*>(
            outB + ((size_t)(node0 + nodel) << 9) + rb) = v;
    }
}

extern "C" void kernel_launch(void* const* d_in, const int* in_sizes, int n_in,
                              void* d_out, int out_size, void* d_ws, size_t ws_size,
                              hipStream_t stream) {
    const int*   video_nodes   = (const int*)d_in[0];
    const int*   neighbors     = (const int*)d_in[1];
    const float* neigh_weights = (const float*)d_in[2];
    const float* emb           = (const float*)d_in[3];
    const float* W1            = (const float*)d_in[4];
    const float* b1            = (const float*)d_in[5];
    float*       out           = (float*)d_out;

    __hip_bfloat16* W1T = (__hip_bfloat16*)d_ws;   // 64 KB

    prep_w1t_kernel<<<DD * 256 / 256, 256, 0, stream>>>(W1, W1T);

    const int nodes_per_block = WPB * MM;                          // 64
    const int grid = (NN + nodes_per_block - 1) / nodes_per_block; // 1563
    graphsage_kernel<<<grid, 256, 0, stream>>>(
        video_nodes, neighbors, neigh_weights, emb, W1T, b1, out);
}

// Round 10
// 204.210 us; speedup vs baseline: 15.6703x; 15.6703x over previous
//
#include <hip/hip_runtime.h>
#include <hip/hip_bf16.h>

// GraphSAGE fused gather + weighted-mean + Linear(256->128) + ReLU
// N=100000, K=16, D=128, V=1e6 rows (f32 table).
//
// Round 10: phased gathers via per-wave presorted item streams + LDS partials.
//  - prep_sort: one wave per output-wave (16 nodes, 256 neighbor items).
//    Ballot-based stable counting sort into 5 index-range buckets
//    (PHSZ=200k). Item = uint2{ idx | m<<20, w/wsum }. Buckets padded to
//    multiples of 4 with {0,0} (m=0,w=0 -> exact no-op). Deterministic.
//  - main phase loop: flat per-(wave,phase) item stream, unrolled x4:
//    4 broadcast item loads + 4 full-row float2/lane loads (batched -> MLP)
//    + 4 LDS float2 read-modify-writes (in-order DS pipe -> same-node safe).
//    NO persistent VGPR accumulators -> spill-impossible (r6/7/9 failure);
//    dense long loops -> no per-node serialization (r8 failure).
//  - phases converge chip-wide -> per-phase working set ~82 MB, ~2.5 phases
//    live < 256 MB L3 -> duplicate rows hit L3 instead of HBM.
//  - pack (partials->bf16 comb), self gather, MFMA vs W1T, full-row epilogue
//    are round-8's verified code (absmax 0.0156).

#define NN 100000
#define KK 16
#define DD 128
#define MM 16            // nodes per wave
#define WPB 4            // waves per block
#define NPHASE 5
#define PHSZ 200000
#define CAP_WP 128       // item slots per (wave,phase)
#define NWAVE (NN / MM)  // 6250

typedef __attribute__((ext_vector_type(8))) short short8;   // 8 x bf16
typedef __attribute__((ext_vector_type(4))) float f32x4;

// ---- prep 1: W1T[d][k] = bf16(W1[k][d]) ----
__global__ __launch_bounds__(256)
void prep_w1t_kernel(const float* __restrict__ W1, __hip_bfloat16* __restrict__ W1T)
{
    const int tid = blockIdx.x * blockDim.x + threadIdx.x;  // 32768 threads
    const int d = tid >> 8;
    const int k = tid & 255;
    W1T[d * 256 + k] = __float2bfloat16(W1[k * DD + d]);
}

// ---- prep 2: per output-wave, bucket 256 items into 5 phase segments ----
__global__ __launch_bounds__(256)
void prep_sort_kernel(const int* __restrict__ neighbors,
                      const float* __restrict__ neigh_weights,
                      uint2* __restrict__ list,
                      unsigned* __restrict__ cnt)
{
    const int lane = threadIdx.x & 63;
    const int w = blockIdx.x * WPB + (threadIdx.x >> 6);   // output wave id
    if (w >= NWAVE) return;
    const int node0 = w * MM;

    // lane L owns items j=4L..4L+3 (node-major, k-minor); 16%4==0 ->
    // all 4 items belong to node m = L>>2.
    const int4   iv = *reinterpret_cast<const int4*>(
        neighbors + node0 * KK + 4 * lane);
    const float4 wv = *reinterpret_cast<const float4*>(
        neigh_weights + node0 * KK + 4 * lane);
    const int   idx[4] = {iv.x, iv.y, iv.z, iv.w};
    const float wt[4]  = {wv.x, wv.y, wv.z, wv.w};
    const int m = lane >> 2;

    // per-node wsum: reduce across the 4-lane group
    float s = wt[0] + wt[1] + wt[2] + wt[3];
    s += __shfl_xor(s, 1);
    s += __shfl_xor(s, 2);
    const float inv = 1.0f / s;

    int ph[4];
    #pragma unroll
    for (int q = 0; q < 4; ++q)
        ph[q] = (idx[q] >= PHSZ) + (idx[q] >= 2 * PHSZ) +
                (idx[q] >= 3 * PHSZ) + (idx[q] >= 4 * PHSZ);

    const unsigned long long lt = (1ull << lane) - 1ull;
    uint2* const row = list + (size_t)w * (NPHASE * CAP_WP);

    unsigned o0 = 0, o1 = 0, o2 = 0, o3 = 0, o4 = 0;   // running bucket fills
    #pragma unroll
    for (int q = 0; q < 4; ++q) {
        const int ps = ph[q];
        const unsigned long long k0 = __ballot(ps == 0);
        const unsigned long long k1 = __ballot(ps == 1);
        const unsigned long long k2 = __ballot(ps == 2);
        const unsigned long long k3 = __ballot(ps == 3);
        const unsigned long long k4 = __ballot(ps == 4);
        const unsigned long long mym =
            ps == 0 ? k0 : ps == 1 ? k1 : ps == 2 ? k2 : ps == 3 ? k3 : k4;
        const unsigned ob =
            ps == 0 ? o0 : ps == 1 ? o1 : ps == 2 ? o2 : ps == 3 ? o3 : o4;
        const unsigned rank = ob + (unsigned)__popcll(mym & lt);
        uint2 item;
        item.x = (unsigned)idx[q] | ((unsigned)m << 20);   // idx < 2^20
        item.y = __float_as_uint(wt[q] * inv);
        row[ps * CAP_WP + rank] = item;
        o0 += (unsigned)__popcll(k0);
        o1 += (unsigned)__popcll(k1);
        o2 += (unsigned)__popcll(k2);
        o3 += (unsigned)__popcll(k3);
        o4 += (unsigned)__popcll(k4);
    }

    // pad each bucket to a multiple of 4 with {0,0} (m=0, w=0 -> no-op)
    const uint2 z = {0u, 0u};
#define FINISH(P, OP)                                                        \
    do {                                                                     \
        const unsigned n4 = (OP + 3u) & ~3u;                                 \
        if ((unsigned)lane < n4 - OP) row[(P) * CAP_WP + OP + lane] = z;     \
        if (lane == 0) cnt[w * NPHASE + (P)] = n4;                           \
    } while (0)
    FINISH(0, o0); FINISH(1, o1); FINISH(2, o2); FINISH(3, o3); FINISH(4, o4);
#undef FINISH
}

static __device__ __forceinline__ unsigned pk_bf16(float a, float b) {
    __hip_bfloat162 t;
    t.x = __float2bfloat16(a);
    t.y = __float2bfloat16(b);
    return *reinterpret_cast<unsigned*>(&t);
}

__global__ __launch_bounds__(256)
void graphsage_kernel(const int* __restrict__ video_nodes,
                      const uint2* __restrict__ list,
                      const unsigned* __restrict__ cnt,
                      const float* __restrict__ emb,
                      const __hip_bfloat16* __restrict__ W1T,
                      const float* __restrict__ b1,
                      float* __restrict__ out)
{
    // per-wave 8 KB slot, three lifetimes:
    //  (a) phase loop: f32 partials [16 nodes][128] (lane: 8B at m*512+8L)
    //  (b) comb bf16 [16 nodes][256 k], XOR-swizzled
    //  (c) epilogue f32 out [16 nodes][128 d], XOR-swizzled
    __shared__ __hip_bfloat16 comb[WPB][MM][2 * DD];

    const int lane = threadIdx.x & 63;
    const int wib  = __builtin_amdgcn_readfirstlane(threadIdx.x >> 6);
    const int w    = blockIdx.x * WPB + wib;
    const int node0 = w * MM;
    if (node0 >= NN) return;   // whole-wave exit; no barriers anywhere

    char* const slot = (char*)&comb[wib][0][0];
    const char* const embB = (const char*)emb;
    char* const outB = (char*)out;
    const unsigned loff = 8u * (unsigned)lane;

    // ---- zero partials ----
    #pragma unroll
    for (int m = 0; m < MM; ++m)
        *reinterpret_cast<float2*>(slot + m * 512 + loff) = make_float2(0.f, 0.f);

    // ---- phase sweep: flat item streams, 4-wide batches ----
    const uint2* const wrow = list + (size_t)w * (NPHASE * CAP_WP);
    #pragma unroll 1
    for (int p = 0; p < NPHASE; ++p) {
        const unsigned n4 = cnt[w * NPHASE + p];          // padded to %4
        const uint2* sp = wrow + p * CAP_WP;
        #pragma unroll 1
        for (unsigned i = 0; i < n4; i += 4) {
            const uint2 t0 = sp[i + 0];                   // wave-uniform
            const uint2 t1 = sp[i + 1];
            const uint2 t2 = sp[i + 2];
            const uint2 t3 = sp[i + 3];
            // 4 full-row loads (512 B/wave each), batched -> MLP
            const float2 e0 = *reinterpret_cast<const float2*>(
                embB + (((t0.x & 0xFFFFFu) << 9) + loff));
            const float2 e1 = *reinterpret_cast<const float2*>(
                embB + (((t1.x & 0xFFFFFu) << 9) + loff));
            const float2 e2 = *reinterpret_cast<const float2*>(
                embB + (((t2.x & 0xFFFFFu) << 9) + loff));
            const float2 e3 = *reinterpret_cast<const float2*>(
                embB + (((t3.x & 0xFFFFFu) << 9) + loff));
            // 4 LDS RMWs; DS pipe is in-order per wave -> same-node safe
            {
                char* const a = slot + (t0.x >> 20) * 512 + loff;
                const float wk = __uint_as_float(t0.y);
                float2 v = *reinterpret_cast<const float2*>(a);
                v.x = fmaf(wk, e0.x, v.x); v.y = fmaf(wk, e0.y, v.y);
                *reinterpret_cast<float2*>(a) = v;
            }
            {
                char* const a = slot + (t1.x >> 20) * 512 + loff;
                const float wk = __uint_as_float(t1.y);
                float2 v = *reinterpret_cast<const float2*>(a);
                v.x = fmaf(wk, e1.x, v.x); v.y = fmaf(wk, e1.y, v.y);
                *reinterpret_cast<float2*>(a) = v;
            }
            {
                char* const a = slot + (t2.x >> 20) * 512 + loff;
                const float wk = __uint_as_float(t2.y);
                float2 v = *reinterpret_cast<const float2*>(a);
                v.x = fmaf(wk, e2.x, v.x); v.y = fmaf(wk, e2.y, v.y);
                *reinterpret_cast<float2*>(a) = v;
            }
            {
                char* const a = slot + (t3.x >> 20) * 512 + loff;
                const float wk = __uint_as_float(t3.y);
                float2 v = *reinterpret_cast<const float2*>(a);
                v.x = fmaf(wk, e3.x, v.x); v.y = fmaf(wk, e3.y, v.y);
                *reinterpret_cast<float2*>(a) = v;
            }
        }
    }

    // ---- pack neigh partials -> comb bf16 (read b64 then write b32) ----
    #pragma unroll
    for (int m = 0; m < MM; ++m) {
        const float2 A =
            *reinterpret_cast<const float2*>(slot + m * 512 + loff);
        const unsigned swz = (unsigned)((m & 7) << 4);
        const unsigned nb =
            ((unsigned)(m * 512 + 256) + 4u * (unsigned)lane) ^ swz;
        *reinterpret_cast<unsigned*>(slot + nb) = pk_bf16(A.x, A.y);
    }

    // ---- self rows: paired float4 gather -> comb lower half ----
    const int half = lane >> 5;
    const int c    = lane & 31;
    const unsigned byte_c = 16u * (unsigned)c;
    #pragma unroll
    for (int mp = 0; mp < MM / 2; ++mp) {
        const int n0 = node0 + 2 * mp;
        const int s0i = video_nodes[n0];
        const int s1i = video_nodes[n0 + 1];
        const int sidx = half ? s1i : s0i;
        const float4 sv = *reinterpret_cast<const float4*>(
            embB + ((((unsigned)sidx) << 9) + byte_c));
        const int nodel = 2 * mp + half;
        const unsigned swz = (unsigned)((nodel & 7) << 4);
        const unsigned sb = ((unsigned)(nodel * 512) + 8u * c) ^ swz;
        uint2 sU;
        sU.x = pk_bf16(sv.x, sv.y);
        sU.y = pk_bf16(sv.z, sv.w);
        *reinterpret_cast<uint2*>(slot + sb) = sU;
    }
    // wave-private slot: same-wave ds ordering via lgkmcnt + data deps.

    // ---- Phase 2: MFMA.  D[d][node] = sum_k W1T[d][k] * comb[node][k] ----
    const int nodeB  = lane & 15;
    const int kchunk = lane >> 4;
    const unsigned swzB = (unsigned)((nodeB & 7) << 4);

    short8 bfrag[8];
    #pragma unroll
    for (int kt = 0; kt < 8; ++kt) {
        const unsigned byte =
            ((unsigned)(nodeB * 512 + kt * 64 + kchunk * 16)) ^ swzB;
        bfrag[kt] = *reinterpret_cast<const short8*>(slot + byte);
    }

    const int drow = lane & 15;
    #pragma unroll
    for (int dt = 0; dt < 8; ++dt) {
        const int d = dt * 16 + drow;
        f32x4 a = {0.0f, 0.0f, 0.0f, 0.0f};
        #pragma unroll
        for (int kt = 0; kt < 8; ++kt) {
            const short8 afrag = *reinterpret_cast<const short8*>(
                &W1T[d * 256 + kt * 32 + kchunk * 8]);
            a = __builtin_amdgcn_mfma_f32_16x16x32_bf16(afrag, bfrag[kt], a,
                                                        0, 0, 0);
        }
        const int d0 = dt * 16 + kchunk * 4;
        const float4 bias = *reinterpret_cast<const float4*>(&b1[d0]);
        f32x4 r;
        r[0] = fmaxf(a[0] + bias.x, 0.0f);
        r[1] = fmaxf(a[1] + bias.y, 0.0f);
        r[2] = fmaxf(a[2] + bias.z, 0.0f);
        r[3] = fmaxf(a[3] + bias.w, 0.0f);
        const unsigned tb = ((unsigned)(nodeB * 512 + d0 * 4)) ^ swzB;
        *reinterpret_cast<f32x4*>(slot + tb) = r;
    }

    // ---- Epilogue: linear LDS read -> full-row contiguous global stores ----
    #pragma unroll
    for (int i = 0; i < 8; ++i) {
        const unsigned o     = (unsigned)i * 1024u + (unsigned)lane * 16u;
        const unsigned nodel = o >> 9;
        const unsigned rb    = o & 511u;
        const unsigned lb    = nodel * 512u + (rb ^ ((nodel & 7u) << 4));
        const float4 v = *reinterpret_cast<const float4*>(slot + lb);
        *reinterpret_cast<float4*>(
            outB + ((size_t)(node0 + nodel) << 9) + rb) = v;
    }
}

extern "C" void kernel_launch(void* const* d_in, const int* in_sizes, int n_in,
                              void* d_out, int out_size, void* d_ws, size_t ws_size,
                              hipStream_t stream) {
    const int*   video_nodes   = (const int*)d_in[0];
    const int*   neighbors     = (const int*)d_in[1];
    const float* neigh_weights = (const float*)d_in[2];
    const float* emb           = (const float*)d_in[3];
    const float* W1            = (const float*)d_in[4];
    const float* b1            = (const float*)d_in[5];
    float*       out           = (float*)d_out;

    char* ws = (char*)d_ws;
    __hip_bfloat16* W1T  = (__hip_bfloat16*)ws;                    // 64 KB
    uint2*          list = (uint2*)(ws + 65536);                   // 32 MB
    unsigned*       cnt  = (unsigned*)(ws + 65536 +
                            (size_t)NWAVE * NPHASE * CAP_WP * 8);  // 125 KB

    prep_w1t_kernel<<<DD * 256 / 256, 256, 0, stream>>>(W1, W1T);
    prep_sort_kernel<<<(NWAVE + WPB - 1) / WPB, 256, 0, stream>>>(
        neighbors, neigh_weights, list, cnt);

    const int nodes_per_block = WPB * MM;                          // 64
    const int grid = (NN + nodes_per_block - 1) / nodes_per_block; // 1563
    graphsage_kernel<<<grid, 256, 0, stream>>>(
        video_nodes, list, cnt, emb, W1T, b1, out);
}

// Round 12
// 166.995 us; speedup vs baseline: 19.1624x; 1.2229x over previous
//
#include <hip/hip_runtime.h>
#include <hip/hip_bf16.h>

// GraphSAGE fused gather + weighted-mean + Linear(256->128) + ReLU
// N=100000, K=16, D=128, V=1e6 rows (f32 table).
//
// Round 12 = round 11 with the nontemporal-store type fixed (ext-vector
// f32x4 instead of HIP float4; __builtin_nontemporal_store requires a
// pointer to scalar/vector type).
//
// Round 5 ledger: FETCH ~700 MB @ ~4.5 TB/s effective on random 512B row
// gathers (vs 7.0 TB/s streaming on same run) -> fetch-path bound. Rounds
// 6-10 proved phase-partitioned gathers can't beat this (best 204 us).
// This round: keep the 51 MB output stream out of L2/L3 (nontemporal
// stores) so it stops evicting live table rows.

#define NN 100000
#define KK 16
#define DD 128
#define MM 16          // nodes per wave
#define WPB 4          // waves per block

typedef __attribute__((ext_vector_type(8))) short short8;   // 8 x bf16
typedef __attribute__((ext_vector_type(4))) float f32x4;

// ---- prep: W1T[d][k] = bf16(W1[k][d]) ----
__global__ __launch_bounds__(256)
void prep_w1t_kernel(const float* __restrict__ W1, __hip_bfloat16* __restrict__ W1T)
{
    const int tid = blockIdx.x * blockDim.x + threadIdx.x;  // 32768 threads
    const int d = tid >> 8;      // 0..127
    const int k = tid & 255;     // 0..255
    W1T[d * 256 + k] = __float2bfloat16(W1[k * DD + d]);
}

static __device__ __forceinline__ unsigned pk_bf16(float a, float b) {
    __hip_bfloat162 t;
    t.x = __float2bfloat16(a);
    t.y = __float2bfloat16(b);
    return *reinterpret_cast<unsigned*>(&t);
}

__global__ __launch_bounds__(256, 4)
void graphsage_kernel(const int* __restrict__ video_nodes,
                      const int* __restrict__ neighbors,
                      const float* __restrict__ neigh_weights,
                      const float* __restrict__ emb,
                      const __hip_bfloat16* __restrict__ W1T,
                      const float* __restrict__ b1,
                      float* __restrict__ out)
{
    // per-wave slot: phase 1/2: [MM nodes][256 k] bf16 = 8 KB;
    // epilogue reuses it as [MM nodes][128 d] f32 (same 512 B/node geometry).
    __shared__ __hip_bfloat16 comb[WPB][MM][2 * DD];

    const int lane = threadIdx.x & 63;
    const int wib  = __builtin_amdgcn_readfirstlane(threadIdx.x >> 6);
    const int node0 = (blockIdx.x * WPB + wib) * MM;
    if (node0 >= NN) return;   // 6250 full waves; trailing waves exit whole

    char* const slot = (char*)&comb[wib][0][0];
    const char* const embB = (const char*)emb;
    char* const outB = (char*)out;

    const int half = lane >> 5;               // which node of the pair
    const int c    = lane & 31;               // column group: floats 4c..4c+3
    const unsigned byte_c = 16u * (unsigned)c;

    // ---- Phase 1: paired gathers + weighted mean, pack bf16 into LDS ----
    #pragma unroll 2
    for (int mp = 0; mp < MM / 2; ++mp) {
        const int n0 = node0 + 2 * mp;        // wave-uniform
        const int n1 = n0 + 1;

        const int s0i = video_nodes[n0];      // scalar
        const int s1i = video_nodes[n1];      // scalar
        const int sidx = half ? s1i : s0i;
        const float4 sv = *reinterpret_cast<const float4*>(
            embB + ((((unsigned)sidx) << 9) + byte_c));

        f32x4 acc = {0.0f, 0.0f, 0.0f, 0.0f};
        float wsum = 0.0f;
        #pragma unroll
        for (int k = 0; k < KK; ++k) {
            const int   i0 = neighbors[n0 * KK + k];        // scalar
            const int   i1 = neighbors[n1 * KK + k];        // scalar
            const float w0 = neigh_weights[n0 * KK + k];    // scalar
            const float w1 = neigh_weights[n1 * KK + k];    // scalar
            const int   rk = half ? i1 : i0;                // cndmask
            const float wk = half ? w1 : w0;                // cndmask
            wsum += wk;
            const float4 e = *reinterpret_cast<const float4*>(
                embB + ((((unsigned)rk) << 9) + byte_c));   // saddr + 32b voff
            acc[0] = fmaf(wk, e.x, acc[0]);
            acc[1] = fmaf(wk, e.y, acc[1]);
            acc[2] = fmaf(wk, e.z, acc[2]);
            acc[3] = fmaf(wk, e.w, acc[3]);
        }
        const float inv = 1.0f / wsum;

        // element j of node's 256-wide comb row lives at byte
        // (node*512 + 2j) ^ ((node&7)<<4); this lane owns self j=4c..4c+3
        // and neigh j=128+4c..128+4c+3 -> two 8 B writes.
        const int nodel = 2 * mp + half;
        const unsigned swz = (unsigned)((nodel & 7) << 4);
        const unsigned sb = ((unsigned)(nodel * 512) + 8u * c) ^ swz;
        const unsigned nb = ((unsigned)(nodel * 512 + 256) + 8u * c) ^ swz;

        uint2 sU, nU;
        sU.x = pk_bf16(sv.x, sv.y);
        sU.y = pk_bf16(sv.z, sv.w);
        nU.x = pk_bf16(acc[0] * inv, acc[1] * inv);
        nU.y = pk_bf16(acc[2] * inv, acc[3] * inv);
        *reinterpret_cast<uint2*>(slot + sb) = sU;
        *reinterpret_cast<uint2*>(slot + nb) = nU;
    }
    // wave-private slot: same-wave ds ordering via lgkmcnt + data deps.

    // ---- Phase 2: MFMA.  D[d][node] = sum_k W1T[d][k] * comb[node][k] ----
    const int nodeB  = lane & 15;    // B col / D col / output node
    const int kchunk = lane >> 4;    // 0..3
    const unsigned swzB = (unsigned)((nodeB & 7) << 4);

    short8 bfrag[8];
    #pragma unroll
    for (int kt = 0; kt < 8; ++kt) {
        const unsigned byte =
            ((unsigned)(nodeB * 512 + kt * 64 + kchunk * 16)) ^ swzB;
        bfrag[kt] = *reinterpret_cast<const short8*>(slot + byte);
    }

    const int drow = lane & 15;      // A row within d-tile
    #pragma unroll
    for (int dt = 0; dt < 8; ++dt) {
        const int d = dt * 16 + drow;
        f32x4 a = {0.0f, 0.0f, 0.0f, 0.0f};
        #pragma unroll
        for (int kt = 0; kt < 8; ++kt) {
            const short8 afrag = *reinterpret_cast<const short8*>(
                &W1T[d * 256 + kt * 32 + kchunk * 8]);
            a = __builtin_amdgcn_mfma_f32_16x16x32_bf16(afrag, bfrag[kt], a,
                                                        0, 0, 0);
        }
        // D: col = lane&15 = node, row = kchunk*4 + reg = d within tile.
        // Stage bias+ReLU in the slot (f32, [node][128d], swizzled); a
        // depends on all bfrag reads -> ds_writes ordered after ds_reads.
        const int d0 = dt * 16 + kchunk * 4;
        const float4 bias = *reinterpret_cast<const float4*>(&b1[d0]);
        f32x4 r;
        r[0] = fmaxf(a[0] + bias.x, 0.0f);
        r[1] = fmaxf(a[1] + bias.y, 0.0f);
        r[2] = fmaxf(a[2] + bias.z, 0.0f);
        r[3] = fmaxf(a[3] + bias.w, 0.0f);
        const unsigned tb = ((unsigned)(nodeB * 512 + d0 * 4)) ^ swzB;
        *reinterpret_cast<f32x4*>(slot + tb) = r;
    }

    // ---- Epilogue: linear LDS read -> full-row contiguous NT stores.
    // Instruction i: lanes 0-31 cover row (2i) bytes 0..511, lanes 32-63
    // row (2i+1). Nontemporal: don't let the 51 MB output stream evict
    // live table rows from L2/L3.
    #pragma unroll
    for (int i = 0; i < 8; ++i) {
        const unsigned o     = (unsigned)i * 1024u + (unsigned)lane * 16u;
        const unsigned nodel = o >> 9;
        const unsigned rb    = o & 511u;
        const unsigned lb    = nodel * 512u + (rb ^ ((nodel & 7u) << 4));
        const f32x4 v = *reinterpret_cast<const f32x4*>(slot + lb);
        __builtin_nontemporal_store(
            v, reinterpret_cast<f32x4*>(
                   outB + ((size_t)(node0 + nodel) << 9) + rb));
    }
}

extern "C" void kernel_launch(void* const* d_in, const int* in_sizes, int n_in,
                              void* d_out, int out_size, void* d_ws, size_t ws_size,
                              hipStream_t stream) {
    const int*   video_nodes   = (const int*)d_in[0];
    const int*   neighbors     = (const int*)d_in[1];
    const float* neigh_weights = (const float*)d_in[2];
    const float* emb           = (const float*)d_in[3];
    const float* W1            = (const float*)d_in[4];
    const float* b1            = (const float*)d_in[5];
    float*       out           = (float*)d_out;

    __hip_bfloat16* W1T = (__hip_bfloat16*)d_ws;   // 64 KB

    prep_w1t_kernel<<<DD * 256 / 256, 256, 0, stream>>>(W1, W1T);

    const int nodes_per_block = WPB * MM;                          // 64
    const int grid = (NN + nodes_per_block - 1) / nodes_per_block; // 1563
    graphsage_kernel<<<grid, 256, 0, stream>>>(
        video_nodes, neighbors, neigh_weights, emb, W1T, b1, out);
}